// Round 4
// baseline (19100.317 us; speedup 1.0000x reference)
//
#include <hip/hip_runtime.h>
#include <hip/hip_bf16.h>
#include <hip/hip_fp16.h>

// Persistent pipelined LSTM decoder. B=64, E=H=1024, 4H=4096, T=1024, L=3, O=64.
// 256 blocks x 256 threads, weights register/LDS-resident.
// R4: device-scope (sc1) producer stores (MALL, not HBM), direct-poll flag
// barrier (no aggregator), padded LDS weight tile, single-pass K-exchange.

typedef _Float16 v8h __attribute__((ext_vector_type(8)));
typedef _Float16 v4h __attribute__((ext_vector_type(4)));
typedef float v4f __attribute__((ext_vector_type(4)));
typedef unsigned uint4v __attribute__((ext_vector_type(4)));

#define NSTEPS 1029

__device__ inline void store16_dev(void* p, v8h v) {
    asm volatile("global_store_dwordx4 %0, %1, off sc1" :: "v"(p), "v"(v) : "memory");
}
__device__ inline void store8_dev(void* p, unsigned long long v) {
    asm volatile("global_store_dwordx2 %0, %1, off sc1" :: "v"(p), "v"(v) : "memory");
}
__device__ inline uint4v load16_dev(const void* p) {
    uint4v v;
    asm volatile("global_load_dwordx4 %0, %1, off sc1\n\ts_waitcnt vmcnt(0)"
                 : "=v"(v) : "v"(p) : "memory");
    return v;
}

__global__ void cvt4_kernel(const float* __restrict__ s, _Float16* __restrict__ d, int n4) {
    int i = blockIdx.x * blockDim.x + threadIdx.x;
    int stride = gridDim.x * blockDim.x;
    for (; i < n4; i += stride) {
        v4f v = ((const v4f*)s)[i];
        v4h o;
        o[0] = (_Float16)v[0]; o[1] = (_Float16)v[1];
        o[2] = (_Float16)v[2]; o[3] = (_Float16)v[3];
        ((v4h*)d)[i] = o;
    }
}

// hbuf [3 layer][2 slot][64 b][1024 j] f16; slot1 = h[-1]
__global__ void hinit_kernel(const float* __restrict__ h0, _Float16* __restrict__ hbuf) {
    int i = blockIdx.x * 256 + threadIdx.x;   // 768*256 = 196608
    int l = i >> 16, rem = i & 65535;
    hbuf[(l * 2 + 1) * 65536 + rem] = (_Float16)h0[i];
}

__global__ void zflags_kernel(unsigned* f) { int i = threadIdx.x; if (i < 260) f[i] = 0u; }

// xp0[b][g] = enc @ Wih0^T + b_ih0 + b_hh0  (validated R1-R3)
__global__ __launch_bounds__(256) void xp0_kernel(
    const _Float16* __restrict__ enc16, const _Float16* __restrict__ Wih,
    const float* __restrict__ b_ih, const float* __restrict__ b_hh,
    float* __restrict__ xp0) {
    __shared__ float red[16384];
    const int tid = threadIdx.x, bx = blockIdx.x;
    const int ln = tid & 63, w = tid >> 6, lm = ln & 15, q = ln >> 4;
    v4f acc[4][4] = {};
    for (int kb = 0; kb < 8; ++kb) {
        int kk = (w + 4 * kb) * 32 + q * 8;
        v8h af[4], bf[4];
#pragma unroll
        for (int mt = 0; mt < 4; ++mt) af[mt] = *(const v8h*)(enc16 + (mt * 16 + lm) * 1024 + kk);
#pragma unroll
        for (int nt = 0; nt < 4; ++nt) bf[nt] = *(const v8h*)(Wih + (bx * 64 + nt * 16 + lm) * 1024 + kk);
#pragma unroll
        for (int mt = 0; mt < 4; ++mt)
#pragma unroll
            for (int nt = 0; nt < 4; ++nt)
                acc[mt][nt] = __builtin_amdgcn_mfma_f32_16x16x32_f16(af[mt], bf[nt], acc[mt][nt], 0, 0, 0);
    }
#pragma unroll
    for (int mt = 0; mt < 4; ++mt) if (mt != w)
#pragma unroll
        for (int nt = 0; nt < 4; ++nt)
            *(v4f*)&red[((w * 16 + mt * 4 + nt) * 64 + ln) * 4] = acc[mt][nt];
    __syncthreads();
#pragma unroll
    for (int ww = 0; ww < 4; ++ww) if (ww != w)
#pragma unroll
        for (int nt = 0; nt < 4; ++nt)
            acc[w][nt] += *(const v4f*)&red[((ww * 16 + w * 4 + nt) * 64 + ln) * 4];
#pragma unroll
    for (int nt = 0; nt < 4; ++nt) {
        int g = bx * 64 + nt * 16 + lm;
        float bb = b_ih[g] + b_hh[g];
#pragma unroll
        for (int r = 0; r < 4; ++r) {
            int b = w * 16 + q * 4 + r;
            xp0[b * 4096 + g] = acc[w][nt][r] + bb;
        }
    }
}

__global__ __launch_bounds__(256, 1) void lstm_persist(
    const _Float16* __restrict__ Wih16,   // [3][4096][1024]
    const _Float16* __restrict__ Whh16,   // [3][4096][1024]
    const _Float16* __restrict__ Wlin16,  // [64][1024]
    const float* __restrict__ xp0,        // [64][4096]
    const float* __restrict__ b_ih,
    const float* __restrict__ b_hh,
    const float* __restrict__ c0,         // [3][64][1024]
    const float* __restrict__ blin,       // [64]
    _Float16* __restrict__ hbuf,          // [3][2][64][1024]
    _Float16* __restrict__ pbuf,          // [2 lp][2 slot][4096 g][64 b]
    float* __restrict__ out,              // [64][1024][64]
    unsigned* __restrict__ flags)         // [256]
{
    __shared__ v4f red[4608];           // 72 KB single-pass exchange [m][dst][si][ln]
    __shared__ _Float16 ldsW[16512];    // 33 KB: 6th unit, padded stride 1032
    __shared__ _Float16 hsh[1024];      // 2 KB h-transpose tile
    const int b = blockIdx.x, tid = threadIdx.x;
    const int ln = tid & 63, w = tid >> 6, lm = ln & 15, q = ln >> 4;
    const int bt0 = w * 16 + q * 4;

    // ---------------- role resolution (uniform) ----------------
    const bool isFin = b < 192;
    const int l = b >> 6, hs = b & 63;
    int sidR[5], sidL; bool hasL;
    if (isFin) {
        hasL = true;
        sidR[0] = sidR[1] = sidR[2] = sidR[3] = -1; sidR[4] = -2;
        int s4;
        if (b < 64) s4 = b;                        // G1 tile b       (asel 0 == l)
        else if (b < 128) s4 = 256 + (b - 64);     // G3 tile b-64    (asel 1 == l)
        else if (b < 132) s4 = 512 + (b - 128);    // proj tile       (asel 2 == l)
        else s4 = 64 + (b - 132);                  // G1 tiles 64..123
        sidL = s4;
    } else {
        int j = b - 192;
        int i0 = (j < 60) ? 5 * j : 300 + 6 * (j - 60);
        hasL = (j >= 60);
        // pool singles list: [G1 124..255] ++ [G3 64..255]  (324 ids)
#pragma unroll
        for (int u = 0; u < 5; ++u) { int id = i0 + u; sidR[u] = (id < 132) ? 124 + id : 188 + id; }
        sidL = hasL ? 188 + i0 + 5 : -2;
    }

    const _Float16* wb[6]; int asel[6], lo[6], hi[6], pcol[6], pl[6]; bool prj[6], act[6];
#pragma unroll
    for (int m = 0; m < 6; ++m) {
        int sd = (m < 5) ? sidR[m] : sidL;
        act[m] = (isFin && m < 4) || sd >= 0;
        prj[m] = false; pl[m] = 0; pcol[m] = 0;
        if (isFin && m < 4) {
            wb[m] = Whh16 + l * 4194304 + (m * 1024 + hs * 16) * 1024;
            asel[m] = l; lo[m] = 1 << 30; hi[m] = 0;
        } else if (sd >= 512) {       // proj: Wlin, A=h2
            wb[m] = Wlin16 + (sd - 512) * 16384;
            asel[m] = 2; lo[m] = 5; hi[m] = 1029; prj[m] = true; pcol[m] = (sd - 512) * 16;
        } else if (sd >= 256) {       // G3: Wih layer2, A=h1
            wb[m] = Wih16 + 2 * 4194304 + (sd - 256) * 16384;
            asel[m] = 1; lo[m] = 3; hi[m] = 1027; pl[m] = 1; pcol[m] = (sd - 256) * 16;
        } else if (sd >= 0) {         // G1: Wih layer1, A=h0
            wb[m] = Wih16 + 4194304 + sd * 16384;
            asel[m] = 0; lo[m] = 1; hi[m] = 1025; pl[m] = 0; pcol[m] = sd * 16;
        } else {
            wb[m] = wb[0]; asel[m] = 0; lo[m] = 1 << 30; hi[m] = 0;
        }
    }
    const int aselP = asel[0];
    int aselS = aselP; bool useS[6]; bool anyS = false;
#pragma unroll
    for (int m = 0; m < 6; ++m) {
        if (!act[m]) asel[m] = aselP;
        useS[m] = (asel[m] != aselP);
        if (useS[m]) { aselS = asel[m]; anyS = true; }
    }

    // ---------------- weights -> registers / LDS (once) ----------------
    const int kofs = w * 256 + q * 8;   // this wave's K-quarter
    v8h wf[5][8];
#pragma unroll
    for (int m = 0; m < 5; ++m) {
        const _Float16* wr = wb[m] + lm * 1024 + kofs;
#pragma unroll
        for (int kb = 0; kb < 8; ++kb) wf[m][kb] = *(const v8h*)(wr + kb * 32);
    }
    if (hasL) {
        const _Float16* wr = wb[5];
        for (int it = tid; it < 2048; it += 256)
            *(v8h*)&ldsW[(it >> 7) * 1032 + ((it & 127) << 3)] = *(const v8h*)(wr + it * 8);
    }
    __syncthreads();

    // ---------------- finisher constants ----------------
    float c4[4] = {0.f, 0.f, 0.f, 0.f};
    float xpr[4][4]; float bsum[4] = {0.f, 0.f, 0.f, 0.f};
    if (isFin) {
#pragma unroll
        for (int r = 0; r < 4; ++r)
            c4[r] = c0[(l * 64 + bt0 + r) * 1024 + hs * 16 + lm];
        if (l == 0) {
#pragma unroll
            for (int u = 0; u < 4; ++u)
#pragma unroll
                for (int r = 0; r < 4; ++r)
                    xpr[u][r] = xp0[(bt0 + r) * 4096 + u * 1024 + hs * 16 + lm];
        } else {
#pragma unroll
            for (int u = 0; u < 4; ++u) {
                int g = u * 1024 + hs * 16 + lm;
                bsum[u] = b_ih[l * 4096 + g] + b_hh[l * 4096 + g];
            }
        }
    }
    float blv = 0.f;
    if (hasL && prj[5]) blv = blin[pcol[5] + lm];

    // ---------------- main loop ----------------
    for (int s = 0; s < NSTEPS; ++s) {
        const unsigned su = (unsigned)(s + 1);
        const int rslot = (s + 1) & 1, wslot = s & 1;
        const int tF = s - 2 * l;
        const bool finValid = isFin && ((unsigned)tF < 1024u);

        // early p-read (layers 1/2), [g][b] layout -> 8B vector loads
        float pv[4][4];
        if (isFin && l >= 1 && finValid) {
            const _Float16* pr = pbuf + ((l - 1) * 2 + (s & 1)) * 262144;
#pragma unroll
            for (int u = 0; u < 4; ++u) {
                v4h t4 = *(const v4h*)&pr[(u * 1024 + hs * 16 + lm) * 64 + bt0];
#pragma unroll
                for (int r = 0; r < 4; ++r) pv[u][r] = (float)t4[r];
            }
        }

        v4f accR[5][4], accL[4];
        const v4f vz = {0.f, 0.f, 0.f, 0.f};
#pragma unroll
        for (int m = 0; m < 5; ++m)
#pragma unroll
            for (int j = 0; j < 4; ++j) accR[m][j] = vz;
#pragma unroll
        for (int j = 0; j < 4; ++j) accL[j] = vz;

        const _Float16* hPb = hbuf + (aselP * 2 + rslot) * 65536 + kofs;
        const _Float16* hSb = hbuf + (aselS * 2 + rslot) * 65536 + kofs;
#pragma unroll
        for (int kb = 0; kb < 8; ++kb) {
            v8h fp[4], fs[4];
#pragma unroll
            for (int j = 0; j < 4; ++j) {
                int mt = (w + j) & 3;                 // rotated M-tile assignment
                fp[j] = *(const v8h*)(hPb + kb * 32 + (mt * 16 + lm) * 1024);
            }
            if (anyS) {
#pragma unroll
                for (int j = 0; j < 4; ++j) {
                    int mt = (w + j) & 3;
                    fs[j] = *(const v8h*)(hSb + kb * 32 + (mt * 16 + lm) * 1024);
                }
            } else {
#pragma unroll
                for (int j = 0; j < 4; ++j) fs[j] = fp[j];
            }
            v8h wl;
            if (hasL) wl = *(const v8h*)&ldsW[lm * 1032 + kofs + kb * 32];
#pragma unroll
            for (int m = 0; m < 5; ++m) {
                if (!act[m]) continue;
#pragma unroll
                for (int j = 0; j < 4; ++j)
                    accR[m][j] = __builtin_amdgcn_mfma_f32_16x16x32_f16(useS[m] ? fs[j] : fp[j], wf[m][kb], accR[m][j], 0, 0, 0);
            }
            if (hasL)
#pragma unroll
                for (int j = 0; j < 4; ++j)
                    accL[j] = __builtin_amdgcn_mfma_f32_16x16x32_f16(useS[5] ? fs[j] : fp[j], wl, accL[j], 0, 0, 0);
        }

        // ---- single-pass cross-wave K reduction: red[m][dst][si][ln] ----
#pragma unroll
        for (int m = 0; m < 6; ++m) {
            bool a = (m < 5) ? act[m] : hasL;
            if (!a) continue;
#pragma unroll
            for (int j = 1; j < 4; ++j) {
                int dst = (w + j) & 3;
                int si = w - (w > dst ? 1 : 0);
                red[((m * 4 + dst) * 3 + si) * 64 + ln] = (m < 5) ? accR[m][j] : accL[j];
            }
        }
        __syncthreads();
#pragma unroll
        for (int m = 0; m < 6; ++m) {
            bool a = (m < 5) ? act[m] : hasL;
            if (!a) continue;
#pragma unroll
            for (int si = 0; si < 3; ++si) {
                v4f t = red[((m * 4 + w) * 3 + si) * 64 + ln];
                if (m < 5) accR[m][0] += t; else accL[0] += t;
            }
        }

        // ---- finisher epilogue: LSTM cell + transpose + 16B device stores ----
        if (isFin) {
            float hv[4];
            if (finValid) {
#pragma unroll
                for (int r = 0; r < 4; ++r) {
                    float gi = accR[0][0][r], gf = accR[1][0][r], gg = accR[2][0][r], go_ = accR[3][0][r];
                    if (l == 0) { gi += xpr[0][r]; gf += xpr[1][r]; gg += xpr[2][r]; go_ += xpr[3][r]; }
                    else { gi += bsum[0] + pv[0][r]; gf += bsum[1] + pv[1][r];
                           gg += bsum[2] + pv[2][r]; go_ += bsum[3] + pv[3][r]; }
                    gi = 1.f / (1.f + __expf(-gi));
                    gf = 1.f / (1.f + __expf(-gf));
                    go_ = 1.f / (1.f + __expf(-go_));
                    gg = 2.f / (1.f + __expf(-2.f * gg)) - 1.f;
                    float c = gf * c4[r] + gi * gg;
                    c4[r] = c;
                    float th = 2.f / (1.f + __expf(-2.f * c)) - 1.f;
                    hv[r] = go_ * th;
                }
#pragma unroll
                for (int r = 0; r < 4; ++r) hsh[(bt0 + r) * 16 + lm] = (_Float16)hv[r];
            }
            __syncthreads();
            if (finValid && tid < 128) {
                int row = tid >> 1, half = tid & 1;
                v8h hv8 = *(v8h*)&hsh[row * 16 + half * 8];
                store16_dev(hbuf + (l * 2 + wslot) * 65536 + row * 1024 + hs * 16 + half * 8, hv8);
            }
        }

        // ---- singles epilogue: p-partials (8B dev) / projection (plain) ----
#pragma unroll
        for (int m = 0; m < 6; ++m) {
            if (isFin && m < 4) continue;
            if (!act[m]) continue;
            if (s < lo[m] || s >= hi[m]) continue;
            v4f a = (m < 5) ? accR[m][0] : accL[0];
            if (prj[m]) {
                int t = s - 5;
#pragma unroll
                for (int r = 0; r < 4; ++r)
                    out[((bt0 + r) * 1024 + t) * 64 + pcol[m] + lm] = a[r] + blv;
            } else {
                union { unsigned long long u64; _Float16 h4[4]; } pk;
#pragma unroll
                for (int r = 0; r < 4; ++r) pk.h4[r] = (_Float16)a[r];
                store8_dev(pbuf + (pl[m] * 2 + ((s + 1) & 1)) * 262144 + (pcol[m] + lm) * 64 + bt0, pk.u64);
            }
        }

        // ---- barrier: drain, flag store, direct 256-flag poll, acquire ----
        asm volatile("s_waitcnt vmcnt(0)" ::: "memory");
        __syncthreads();
        if (tid == 0)
            __hip_atomic_store(&flags[b], su, __ATOMIC_RELAXED, __HIP_MEMORY_SCOPE_AGENT);
        if (tid < 64) {
            const unsigned* fp4 = flags + tid * 4;
            for (;;) {
                uint4v v = load16_dev(fp4);
                bool ok = v[0] >= su && v[1] >= su && v[2] >= su && v[3] >= su;
                if (__ballot(ok) == ~0ull) break;
                __builtin_amdgcn_s_sleep(1);
            }
        }
        if (tid == 0)
            (void)__hip_atomic_load(&flags[0], __ATOMIC_ACQUIRE, __HIP_MEMORY_SCOPE_AGENT);
        __syncthreads();
    }
}

extern "C" void kernel_launch(void* const* d_in, const int* in_sizes, int n_in,
                              void* d_out, int out_size, void* d_ws, size_t ws_size,
                              hipStream_t stream) {
    const float* enc   = (const float*)d_in[0];
    const float* h0    = (const float*)d_in[1];
    const float* c0    = (const float*)d_in[2];
    const float* W_ih  = (const float*)d_in[3];
    const float* W_hh  = (const float*)d_in[4];
    const float* b_ih  = (const float*)d_in[5];
    const float* b_hh  = (const float*)d_in[6];
    const float* W_lin = (const float*)d_in[7];
    const float* b_lin = (const float*)d_in[8];
    float* out = (float*)d_out;
    char* ws = (char*)d_ws;

    _Float16* Wih16  = (_Float16*)(ws);                 // 25165824 B
    _Float16* Whh16  = (_Float16*)(ws + 25165824);      // 25165824 B
    _Float16* Wlin16 = (_Float16*)(ws + 50331648);      // 131072 B
    _Float16* enc16  = (_Float16*)(ws + 50462720);      // 131072 B (reused: flags after xp0)
    float*    xp0    = (float*)   (ws + 50593792);      // 1048576 B
    _Float16* hbuf   = (_Float16*)(ws + 51642368);      // 786432 B
    _Float16* pbuf   = (_Float16*)(ws + 52428800);      // 2097152 B
    unsigned* flags  = (unsigned*)(ws + 50462720);      // aliases enc16 (dead after xp0)

    cvt4_kernel<<<2048, 256, 0, stream>>>(W_ih, Wih16, 3145728);
    cvt4_kernel<<<2048, 256, 0, stream>>>(W_hh, Whh16, 3145728);
    cvt4_kernel<<<64, 256, 0, stream>>>(W_lin, Wlin16, 16384);
    cvt4_kernel<<<64, 256, 0, stream>>>(enc, enc16, 16384);
    hinit_kernel<<<768, 256, 0, stream>>>(h0, hbuf);
    xp0_kernel<<<64, 256, 0, stream>>>(enc16, Wih16, b_ih, b_hh, xp0);
    zflags_kernel<<<1, 512, 0, stream>>>(flags);   // after xp0: enc16 region is dead

    lstm_persist<<<256, 256, 0, stream>>>(Wih16, Whh16, Wlin16, xp0, b_ih, b_hh,
                                          c0, b_lin, hbuf, pbuf, out, flags);
}